// Round 1
// baseline (723.093 us; speedup 1.0000x reference)
//
#include <hip/hip_runtime.h>
#include <cstdint>
#include <cmath>

// ---------- types ----------
typedef __attribute__((ext_vector_type(4))) short s16x4;
typedef __attribute__((ext_vector_type(8))) short s16x8;
typedef __attribute__((ext_vector_type(4))) float f32x4;

#define MFMA_16x16x32_BF16(a,b,c) __builtin_amdgcn_mfma_f32_16x16x32_bf16(a,b,c,0,0,0)

#if defined(__has_builtin)
#if __has_builtin(__builtin_amdgcn_mfma_f32_16x16x16bf16_1k)
#define HAVE_MFMA16 1
#endif
#endif

__device__ __forceinline__ f32x4 mfma16(s16x4 a, s16x4 b, f32x4 c) {
#ifdef HAVE_MFMA16
  return __builtin_amdgcn_mfma_f32_16x16x16bf16_1k(a, b, c, 0, 0, 0);
#else
  asm volatile("v_mfma_f32_16x16x16_bf16 %0, %1, %2, %0" : "+v"(c) : "v"(a), "v"(b));
  return c;
#endif
}

__device__ __forceinline__ short f2bf(float f) {
  union { float f; uint32_t u; } v; v.f = f;
  uint32_t r = (v.u + 0x7fffu + ((v.u >> 16) & 1u)) >> 16;
  return (short)r;
}
__device__ __forceinline__ float bf2f(short s) {
  union { float f; uint32_t u; } v; v.u = ((uint32_t)(uint16_t)s) << 16;
  return v.f;
}

#define GLOAD_LDS16(g, l) \
  __builtin_amdgcn_global_load_lds((const __attribute__((address_space(1))) void*)(g), \
                                   (__attribute__((address_space(3))) void*)(l), 16, 0, 0)

// ---------- fp32 -> bf16 conversion ----------
__global__ __launch_bounds__(256) void conv_kernel(const float* __restrict__ src,
                                                   short* __restrict__ dst, int n4) {
  int i = blockIdx.x * 256 + threadIdx.x;
  if (i >= n4) return;
  const float4 v = reinterpret_cast<const float4*>(src)[i];
  s16x4 o;
  o[0] = f2bf(v.x); o[1] = f2bf(v.y); o[2] = f2bf(v.z); o[3] = f2bf(v.w);
  reinterpret_cast<s16x4*>(dst)[i] = o;
}

// ---------- GEMM: C[M,N] = A[M,K] * Bw[N,K]^T, K=2048, ldc=2048 ----------
// 128x128 tile, BK=32, 4 waves, 4x4 16x16x32 fragments per wave (m97 structure)
template <typename OutT>
__device__ __forceinline__ void gemm_body(const short* __restrict__ A,
                                          const short* __restrict__ Bw,
                                          OutT* __restrict__ C) {
  __shared__ short As[128 * 32];
  __shared__ short Bs[128 * 32];
  const int tid  = threadIdx.x;
  const int lane = tid & 63;
  const int w    = tid >> 6;
  const int lrow = lane & 15, lhi = lane >> 4;
  const int m0 = blockIdx.y * 128;
  const int n0 = blockIdx.x * 128;
  const int wm = (w >> 1) * 64, wn = (w & 1) * 64;

  f32x4 acc[4][4] = {};

  // staging geometry: 8KB tile = 2 chunks x 4 waves x 64 lanes x 16B
  const int flat0 = w * 1024 + lane * 16;          // byte offset in tile, chunk 0
  const int r0 = flat0 >> 6, c0 = (flat0 & 63) >> 1;
  const int flat1 = flat0 + 4096;
  const int r1 = flat1 >> 6, c1 = (flat1 & 63) >> 1;

  const short* a0 = A  + (size_t)(m0 + r0) * 2048 + c0;
  const short* a1 = A  + (size_t)(m0 + r1) * 2048 + c1;
  const short* b0 = Bw + (size_t)(n0 + r0) * 2048 + c0;
  const short* b1 = Bw + (size_t)(n0 + r1) * 2048 + c1;
  char* lA0 = (char*)As + w * 1024;
  char* lA1 = (char*)As + 4096 + w * 1024;
  char* lB0 = (char*)Bs + w * 1024;
  char* lB1 = (char*)Bs + 4096 + w * 1024;

  for (int k0 = 0; k0 < 2048; k0 += 32) {
    __syncthreads();
    GLOAD_LDS16(a0 + k0, lA0);
    GLOAD_LDS16(a1 + k0, lA1);
    GLOAD_LDS16(b0 + k0, lB0);
    GLOAD_LDS16(b1 + k0, lB1);
    __syncthreads();
    s16x8 af[4], bg[4];
#pragma unroll
    for (int i = 0; i < 4; ++i) {
      af[i] = *reinterpret_cast<const s16x8*>(As + (wm + i * 16 + lrow) * 32 + lhi * 8);
      bg[i] = *reinterpret_cast<const s16x8*>(Bs + (wn + i * 16 + lrow) * 32 + lhi * 8);
    }
#pragma unroll
    for (int i = 0; i < 4; ++i)
#pragma unroll
      for (int j = 0; j < 4; ++j)
        acc[i][j] = MFMA_16x16x32_BF16(af[i], bg[j], acc[i][j]);
  }

#pragma unroll
  for (int i = 0; i < 4; ++i) {
    const int rb = m0 + wm + i * 16 + lhi * 4;
#pragma unroll
    for (int j = 0; j < 4; ++j) {
      const int cb = n0 + wn + j * 16 + lrow;
#pragma unroll
      for (int r = 0; r < 4; ++r) {
        const float v = acc[i][j][r];
        const size_t idx = (size_t)(rb + r) * 2048 + cb;
        if constexpr (__is_same(OutT, float)) C[idx] = v;
        else                                  C[idx] = f2bf(v);
      }
    }
  }
}

__global__ __launch_bounds__(256) void gemm_qkv_kernel(const short* __restrict__ X,
                                                       const short* __restrict__ Wq,
                                                       const short* __restrict__ Wk,
                                                       const short* __restrict__ Wv,
                                                       short* __restrict__ Qp,
                                                       short* __restrict__ Kp,
                                                       short* __restrict__ Vp) {
  const short* W; short* O;
  if (blockIdx.z == 0)      { W = Wq; O = Qp; }
  else if (blockIdx.z == 1) { W = Wk; O = Kp; }
  else                      { W = Wv; O = Vp; }
  gemm_body<short>(X, W, O);
}

__global__ __launch_bounds__(256) void gemm_o_kernel(const short* __restrict__ AO,
                                                     const short* __restrict__ Wo,
                                                     float* __restrict__ out) {
  gemm_body<float>(AO, Wo, out);
}

// ---------- RoPE in-place on Qp,Kp (bf16 pairs packed in u32) + fp32 k output ----------
__global__ __launch_bounds__(256) void rope_kernel(unsigned* __restrict__ Qp,
                                                   unsigned* __restrict__ Kp,
                                                   const float* __restrict__ rc,
                                                   const float* __restrict__ rs,
                                                   float* __restrict__ kout) {
  const unsigned tid = blockIdx.x * 256 + threadIdx.x;  // 2^22 total
  const int j = tid & 63;
  const int h = (tid >> 6) & 15;
  const int s = (tid >> 10) & 2047;
  const int b = tid >> 21;
  const float c  = rc[s * 64 + j];
  const float sn = rs[s * 64 + j];
  const size_t half = ((size_t)(b * 2048 + s) * 2048 + h * 128) / 2 + j;

  const unsigned q = Qp[half];
  const float q1 = bf2f((short)(q & 0xffff)), q2 = bf2f((short)(q >> 16));
  const float qo1 = q1 * c - q2 * sn, qo2 = q1 * sn + q2 * c;
  Qp[half] = ((unsigned)(uint16_t)f2bf(qo1)) | (((unsigned)(uint16_t)f2bf(qo2)) << 16);

  const unsigned k = Kp[half];
  const float k1 = bf2f((short)(k & 0xffff)), k2 = bf2f((short)(k >> 16));
  const float ko1 = k1 * c - k2 * sn, ko2 = k1 * sn + k2 * c;
  Kp[half] = ((unsigned)(uint16_t)f2bf(ko1)) | (((unsigned)(uint16_t)f2bf(ko2)) << 16);

  const size_t kidx = (((size_t)b * 16 + h) * 2048 + s) * 128 + 2 * j;
  *reinterpret_cast<float2*>(kout + kidx) = make_float2(ko1, ko2);
}

// ---------- V: (b,s,h,d) bf16 -> (b,h,s,d) fp32 output chunk ----------
__global__ __launch_bounds__(256) void vcopy_kernel(const short* __restrict__ Vp,
                                                    float* __restrict__ vout) {
  const unsigned tid = blockIdx.x * 256 + threadIdx.x;  // 2^21 total
  const int d4 = tid & 31;
  const int s  = (tid >> 5) & 2047;
  const int h  = (tid >> 16) & 15;
  const int b  = tid >> 20;
  const s16x4 v = *reinterpret_cast<const s16x4*>(
      Vp + (size_t)(b * 2048 + s) * 2048 + h * 128 + d4 * 4);
  float4 o;
  o.x = bf2f(v[0]); o.y = bf2f(v[1]); o.z = bf2f(v[2]); o.w = bf2f(v[3]);
  *reinterpret_cast<float4*>(vout + ((((size_t)b * 16 + h) * 2048 + s) * 128 + d4 * 4)) = o;
}

// ---------- causal flash attention: 1 wave per 16 q-rows ----------
// Sizes: S=2048, hd=128. Q/K/V in (b,s,h,d) bf16 layout, row stride 2048.
// Scores computed swapped: mfma(K,Q) -> S^T so P lands in PV A-operand layout.
__global__ __launch_bounds__(64) void attn_kernel(const short* __restrict__ Qp,
                                                  const short* __restrict__ Kp,
                                                  const short* __restrict__ Vp,
                                                  short* __restrict__ AO) {
  const int lane = threadIdx.x;
  const int lrow = lane & 15, lhi = lane >> 4;
  const int m0 = blockIdx.x * 16;
  const int h = blockIdx.y, b = blockIdx.z;
  const size_t base = (size_t)b * 2048 * 2048 + (size_t)h * 128;
  const short* Q = Qp + base;
  const short* K = Kp + base;
  const short* V = Vp + base;

  s16x8 qf[4];
#pragma unroll
  for (int kk = 0; kk < 4; ++kk)
    qf[kk] = *reinterpret_cast<const s16x8*>(Q + (size_t)(m0 + lrow) * 2048 + kk * 32 + lhi * 8);

  f32x4 o[8] = {};
  float mstate = -INFINITY, lstate = 0.f;
  const float scale = 0.08838834764831845f;  // 1/sqrt(128)
  const int qabs = m0 + lrow;
  const int nkt = m0 / 16 + 1;

  for (int kt = 0; kt < nkt; ++kt) {
    const int sk0 = kt * 16;
    f32x4 sacc = {};
#pragma unroll
    for (int kk = 0; kk < 4; ++kk) {
      const s16x8 kf = *reinterpret_cast<const s16x8*>(
          K + (size_t)(sk0 + lrow) * 2048 + kk * 32 + lhi * 8);
      sacc = MFMA_16x16x32_BF16(kf, qf[kk], sacc);  // C[krow][qcol]
    }
    float p[4];
    float tmax = -1e30f;
#pragma unroll
    for (int r = 0; r < 4; ++r) {
      const int skr = sk0 + lhi * 4 + r;
      const float v = (skr > qabs) ? -1e9f : sacc[r] * scale;
      p[r] = v;
      tmax = fmaxf(tmax, v);
    }
    tmax = fmaxf(tmax, __shfl_xor(tmax, 16));
    tmax = fmaxf(tmax, __shfl_xor(tmax, 32));
    const float mnew = fmaxf(mstate, tmax);
    const float corr = __expf(mstate - mnew);
    float psum = 0.f;
#pragma unroll
    for (int r = 0; r < 4; ++r) { p[r] = __expf(p[r] - mnew); psum += p[r]; }
    psum += __shfl_xor(psum, 16);
    psum += __shfl_xor(psum, 32);
    lstate = lstate * corr + psum;
    mstate = mnew;

    const float cr0 = __shfl(corr, lhi * 4 + 0);
    const float cr1 = __shfl(corr, lhi * 4 + 1);
    const float cr2 = __shfl(corr, lhi * 4 + 2);
    const float cr3 = __shfl(corr, lhi * 4 + 3);
#pragma unroll
    for (int t = 0; t < 8; ++t) {
      o[t][0] *= cr0; o[t][1] *= cr1; o[t][2] *= cr2; o[t][3] *= cr3;
    }

    s16x4 pa;
#pragma unroll
    for (int r = 0; r < 4; ++r) pa[r] = f2bf(p[r]);

#pragma unroll
    for (int t = 0; t < 8; ++t) {
      s16x4 vf;
#pragma unroll
      for (int jj = 0; jj < 4; ++jj)
        vf[jj] = V[(size_t)(sk0 + lhi * 4 + jj) * 2048 + t * 16 + lrow];
      o[t] = mfma16(pa, vf, o[t]);
    }
  }

  const float linv = 1.f / lstate;
  const float ln[4] = { __shfl(linv, lhi * 4 + 0), __shfl(linv, lhi * 4 + 1),
                        __shfl(linv, lhi * 4 + 2), __shfl(linv, lhi * 4 + 3) };
#pragma unroll
  for (int t = 0; t < 8; ++t) {
#pragma unroll
    for (int r = 0; r < 4; ++r) {
      const size_t s = m0 + lhi * 4 + r;
      AO[((size_t)b * 2048 + s) * 2048 + h * 128 + t * 16 + lrow] = f2bf(o[t][r] * ln[r]);
    }
  }
}

// ---------- launch ----------
extern "C" void kernel_launch(void* const* d_in, const int* in_sizes, int n_in,
                              void* d_out, int out_size, void* d_ws, size_t ws_size,
                              hipStream_t stream) {
  const float* hidden = (const float*)d_in[0];
  const float* rcos   = (const float*)d_in[1];
  const float* rsin   = (const float*)d_in[2];
  const float* wq     = (const float*)d_in[3];
  const float* wk     = (const float*)d_in[4];
  const float* wv     = (const float*)d_in[5];
  const float* wo     = (const float*)d_in[6];

  float* out0 = (float*)d_out;                 // (B,S,D)   8388608
  float* kout = out0 + 8388608;                // (B,H,S,hd) 8388608
  float* vout = out0 + 16777216;               // (B,H,S,hd) 8388608

  short* ws  = (short*)d_ws;
  short* Xbf = ws;                  // 8388608 bf16 (also reused as attn-out AO)
  short* Wqb = ws + 8388608;        // 4194304
  short* Wkb = ws + 12582912;
  short* Wvb = ws + 16777216;
  short* Wob = ws + 20971520;
  short* Qp  = ws + 25165824;       // 8388608
  short* Kp  = ws + 33554432;
  short* Vp  = ws + 41943040;       // ends at 50331648 shorts = 100.7 MB

  conv_kernel<<<8192, 256, 0, stream>>>(hidden, Xbf, 2097152);
  conv_kernel<<<4096, 256, 0, stream>>>(wq, Wqb, 1048576);
  conv_kernel<<<4096, 256, 0, stream>>>(wk, Wkb, 1048576);
  conv_kernel<<<4096, 256, 0, stream>>>(wv, Wvb, 1048576);
  conv_kernel<<<4096, 256, 0, stream>>>(wo, Wob, 1048576);

  gemm_qkv_kernel<<<dim3(16, 32, 3), 256, 0, stream>>>(Xbf, Wqb, Wkb, Wvb, Qp, Kp, Vp);

  rope_kernel<<<16384, 256, 0, stream>>>((unsigned*)Qp, (unsigned*)Kp, rcos, rsin, kout);
  vcopy_kernel<<<8192, 256, 0, stream>>>(Vp, vout);

  attn_kernel<<<dim3(128, 16, 2), 64, 0, stream>>>(Qp, Kp, Vp, Xbf /*AO*/);

  gemm_o_kernel<<<dim3(16, 32, 1), 256, 0, stream>>>(Xbf, Wob, out0);
}

// Round 2
// 718.685 us; speedup vs baseline: 1.0061x; 1.0061x over previous
//
#include <hip/hip_runtime.h>
#include <cstdint>
#include <cmath>

// ---------- types ----------
typedef __attribute__((ext_vector_type(4))) short s16x4;
typedef __attribute__((ext_vector_type(8))) short s16x8;
typedef __attribute__((ext_vector_type(4))) float f32x4;

#define MFMA_16x16x32_BF16(a,b,c) __builtin_amdgcn_mfma_f32_16x16x32_bf16(a,b,c,0,0,0)

#if defined(__has_builtin)
#if __has_builtin(__builtin_amdgcn_mfma_f32_16x16x16bf16_1k)
#define HAVE_MFMA16 1
#endif
#endif

__device__ __forceinline__ f32x4 mfma16(s16x4 a, s16x4 b, f32x4 c) {
#ifdef HAVE_MFMA16
  return __builtin_amdgcn_mfma_f32_16x16x16bf16_1k(a, b, c, 0, 0, 0);
#else
  asm volatile("v_mfma_f32_16x16x16_bf16 %0, %1, %2, %0" : "+v"(c) : "v"(a), "v"(b));
  return c;
#endif
}

__device__ __forceinline__ short f2bf(float f) {
  union { float f; uint32_t u; } v; v.f = f;
  uint32_t r = (v.u + 0x7fffu + ((v.u >> 16) & 1u)) >> 16;
  return (short)r;
}
__device__ __forceinline__ float bf2f(short s) {
  union { float f; uint32_t u; } v; v.u = ((uint32_t)(uint16_t)s) << 16;
  return v.f;
}

#define GLOAD_LDS16(g, l) \
  __builtin_amdgcn_global_load_lds((const __attribute__((address_space(1))) void*)(g), \
                                   (__attribute__((address_space(3))) void*)(l), 16, 0, 0)

// ---------- fp32 -> bf16 conversion ----------
__global__ __launch_bounds__(256) void conv_kernel(const float* __restrict__ src,
                                                   short* __restrict__ dst, int n4) {
  int i = blockIdx.x * 256 + threadIdx.x;
  if (i >= n4) return;
  const float4 v = reinterpret_cast<const float4*>(src)[i];
  s16x4 o;
  o[0] = f2bf(v.x); o[1] = f2bf(v.y); o[2] = f2bf(v.z); o[3] = f2bf(v.w);
  reinterpret_cast<s16x4*>(dst)[i] = o;
}

// ---------- GEMM: C[M,N] = A[M,K] * Bw[N,K]^T, K=2048, ldc=2048 ----------
// 128x128 tile, BK=32, 4 waves, 4x4 16x16x32 fragments per wave (m97 structure)
template <typename OutT>
__device__ __forceinline__ void gemm_body(const short* __restrict__ A,
                                          const short* __restrict__ Bw,
                                          OutT* __restrict__ C) {
  __shared__ short As[128 * 32];
  __shared__ short Bs[128 * 32];
  const int tid  = threadIdx.x;
  const int lane = tid & 63;
  const int w    = tid >> 6;
  const int lrow = lane & 15, lhi = lane >> 4;
  const int m0 = blockIdx.y * 128;
  const int n0 = blockIdx.x * 128;
  const int wm = (w >> 1) * 64, wn = (w & 1) * 64;

  f32x4 acc[4][4] = {};

  const int flat0 = w * 1024 + lane * 16;
  const int r0 = flat0 >> 6, c0 = (flat0 & 63) >> 1;
  const int flat1 = flat0 + 4096;
  const int r1 = flat1 >> 6, c1 = (flat1 & 63) >> 1;

  const short* a0 = A  + (size_t)(m0 + r0) * 2048 + c0;
  const short* a1 = A  + (size_t)(m0 + r1) * 2048 + c1;
  const short* b0 = Bw + (size_t)(n0 + r0) * 2048 + c0;
  const short* b1 = Bw + (size_t)(n0 + r1) * 2048 + c1;
  char* lA0 = (char*)As + w * 1024;
  char* lA1 = (char*)As + 4096 + w * 1024;
  char* lB0 = (char*)Bs + w * 1024;
  char* lB1 = (char*)Bs + 4096 + w * 1024;

  for (int k0 = 0; k0 < 2048; k0 += 32) {
    __syncthreads();
    GLOAD_LDS16(a0 + k0, lA0);
    GLOAD_LDS16(a1 + k0, lA1);
    GLOAD_LDS16(b0 + k0, lB0);
    GLOAD_LDS16(b1 + k0, lB1);
    __syncthreads();
    s16x8 af[4], bg[4];
#pragma unroll
    for (int i = 0; i < 4; ++i) {
      af[i] = *reinterpret_cast<const s16x8*>(As + (wm + i * 16 + lrow) * 32 + lhi * 8);
      bg[i] = *reinterpret_cast<const s16x8*>(Bs + (wn + i * 16 + lrow) * 32 + lhi * 8);
    }
#pragma unroll
    for (int i = 0; i < 4; ++i)
#pragma unroll
      for (int j = 0; j < 4; ++j)
        acc[i][j] = MFMA_16x16x32_BF16(af[i], bg[j], acc[i][j]);
  }

#pragma unroll
  for (int i = 0; i < 4; ++i) {
    const int rb = m0 + wm + i * 16 + lhi * 4;
#pragma unroll
    for (int j = 0; j < 4; ++j) {
      const int cb = n0 + wn + j * 16 + lrow;
#pragma unroll
      for (int r = 0; r < 4; ++r) {
        const float v = acc[i][j][r];
        const size_t idx = (size_t)(rb + r) * 2048 + cb;
        if constexpr (__is_same(OutT, float)) C[idx] = v;
        else                                  C[idx] = f2bf(v);
      }
    }
  }
}

__global__ __launch_bounds__(256) void gemm_qkv_kernel(const short* __restrict__ X,
                                                       const short* __restrict__ Wq,
                                                       const short* __restrict__ Wk,
                                                       const short* __restrict__ Wv,
                                                       short* __restrict__ Qp,
                                                       short* __restrict__ Kp,
                                                       short* __restrict__ Vp) {
  const short* W; short* O;
  if (blockIdx.z == 0)      { W = Wq; O = Qp; }
  else if (blockIdx.z == 1) { W = Wk; O = Kp; }
  else                      { W = Wv; O = Vp; }
  gemm_body<short>(X, W, O);
}

__global__ __launch_bounds__(256) void gemm_o_kernel(const short* __restrict__ AO,
                                                     const short* __restrict__ Wo,
                                                     float* __restrict__ out) {
  gemm_body<float>(AO, Wo, out);
}

// ---------- RoPE in-place on Qp,Kp (bf16 pairs packed in u32) + fp32 k output ----------
__global__ __launch_bounds__(256) void rope_kernel(unsigned* __restrict__ Qp,
                                                   unsigned* __restrict__ Kp,
                                                   const float* __restrict__ rc,
                                                   const float* __restrict__ rs,
                                                   float* __restrict__ kout) {
  const unsigned tid = blockIdx.x * 256 + threadIdx.x;  // 2^22 total
  const int j = tid & 63;
  const int h = (tid >> 6) & 15;
  const int s = (tid >> 10) & 2047;
  const int b = tid >> 21;
  const float c  = rc[s * 64 + j];
  const float sn = rs[s * 64 + j];
  const size_t half = ((size_t)(b * 2048 + s) * 2048 + h * 128) / 2 + j;

  const unsigned q = Qp[half];
  const float q1 = bf2f((short)(q & 0xffff)), q2 = bf2f((short)(q >> 16));
  const float qo1 = q1 * c - q2 * sn, qo2 = q1 * sn + q2 * c;
  Qp[half] = ((unsigned)(uint16_t)f2bf(qo1)) | (((unsigned)(uint16_t)f2bf(qo2)) << 16);

  const unsigned k = Kp[half];
  const float k1 = bf2f((short)(k & 0xffff)), k2 = bf2f((short)(k >> 16));
  const float ko1 = k1 * c - k2 * sn, ko2 = k1 * sn + k2 * c;
  Kp[half] = ((unsigned)(uint16_t)f2bf(ko1)) | (((unsigned)(uint16_t)f2bf(ko2)) << 16);

  const size_t kidx = (((size_t)b * 16 + h) * 2048 + s) * 128 + 2 * j;
  *reinterpret_cast<float2*>(kout + kidx) = make_float2(ko1, ko2);
}

// ---------- V: (b,s,h,d) bf16 -> (b,h,s,d) fp32 output chunk ----------
__global__ __launch_bounds__(256) void vcopy_kernel(const short* __restrict__ Vp,
                                                    float* __restrict__ vout) {
  const unsigned tid = blockIdx.x * 256 + threadIdx.x;  // 2^21 total
  const int d4 = tid & 31;
  const int s  = (tid >> 5) & 2047;
  const int h  = (tid >> 16) & 15;
  const int b  = tid >> 20;
  const s16x4 v = *reinterpret_cast<const s16x4*>(
      Vp + (size_t)(b * 2048 + s) * 2048 + h * 128 + d4 * 4);
  float4 o;
  o.x = bf2f(v[0]); o.y = bf2f(v[1]); o.z = bf2f(v[2]); o.w = bf2f(v[3]);
  *reinterpret_cast<float4*>(vout + ((((size_t)b * 16 + h) * 2048 + s) * 128 + d4 * 4)) = o;
}

// ---------- V transpose: (b,s,h,d) bf16 -> (b,h,d,s) bf16 ----------
__global__ __launch_bounds__(256) void vtrans_kernel(const short* __restrict__ Vp,
                                                     short* __restrict__ Vt) {
  __shared__ short tile[64][68];
  const int bh = blockIdx.z;              // b*16+h
  const int b = bh >> 4, h = bh & 15;
  const int s0 = blockIdx.x * 64;
  const int d0 = blockIdx.y * 64;
  const int tid = threadIdx.x;
  const int r  = tid >> 4;                // 0..15
  const int c4 = tid & 15;                // 0..15 (x4 elems)
  const short* src = Vp + ((size_t)(b * 2048 + s0) * 2048) + h * 128 + d0;
#pragma unroll
  for (int j = 0; j < 4; ++j) {
    const int row = r + j * 16;
    const s16x4 v = *reinterpret_cast<const s16x4*>(src + (size_t)row * 2048 + c4 * 4);
    *reinterpret_cast<s16x4*>(&tile[row][c4 * 4]) = v;
  }
  __syncthreads();
  short* dst = Vt + ((size_t)(bh * 128 + d0) * 2048) + s0;
#pragma unroll
  for (int j = 0; j < 4; ++j) {
    const int drow = r + j * 16;
    s16x4 o;
#pragma unroll
    for (int jj = 0; jj < 4; ++jj) o[jj] = tile[c4 * 4 + jj][drow];
    *reinterpret_cast<s16x4*>(dst + (size_t)drow * 2048 + c4 * 4) = o;
  }
}

// ---------- causal flash attention ----------
// 1 wave per 32 q-rows (2 x 16-row fragments), KVBLK=32 outer steps.
// Swapped QK^T: mfma(K,Q) -> S^T so P lands directly in the PV A-operand layout.
// V consumed from transposed Vt (b,h,d,s): PV B-fragments are s16x4 vector loads.
__global__ __launch_bounds__(64) void attn_kernel(const short* __restrict__ Qp,
                                                  const short* __restrict__ Kp,
                                                  const short* __restrict__ Vt,
                                                  short* __restrict__ AO) {
  const int lane = threadIdx.x;
  const int lrow = lane & 15, lhi = lane >> 4;
  const int m0 = (gridDim.x - 1 - blockIdx.x) * 32;  // longest blocks first
  const int h = blockIdx.y, b = blockIdx.z;
  const size_t qk_base = (size_t)b * 2048 * 2048 + (size_t)h * 128;
  const short* Q = Qp + qk_base;
  const short* K = Kp + qk_base;
  const short* V = Vt + ((size_t)(b * 16 + h) * 128) * 2048;  // [d][s]

  s16x8 qf[2][4];
#pragma unroll
  for (int f = 0; f < 2; ++f)
#pragma unroll
    for (int kk = 0; kk < 4; ++kk)
      qf[f][kk] = *reinterpret_cast<const s16x8*>(
          Q + (size_t)(m0 + f * 16 + lrow) * 2048 + kk * 32 + lhi * 8);

  f32x4 o[2][8] = {};
  float mst[2] = {-INFINITY, -INFINITY};
  float lst[2] = {0.f, 0.f};
  const float scale = 0.08838834764831845f;  // 1/sqrt(128)
  const int nkb = m0 / 32 + 1;

  for (int kb = 0; kb < nkb; ++kb) {
    const int sk0 = kb * 32;
    const bool last = (kb == nkb - 1);

    f32x4 sacc[2][2] = {};  // [kfrag g][qfrag f]
    __builtin_amdgcn_s_setprio(1);
#pragma unroll
    for (int kk = 0; kk < 4; ++kk) {
      const s16x8 kf0 = *reinterpret_cast<const s16x8*>(
          K + (size_t)(sk0 + lrow) * 2048 + kk * 32 + lhi * 8);
      const s16x8 kf1 = *reinterpret_cast<const s16x8*>(
          K + (size_t)(sk0 + 16 + lrow) * 2048 + kk * 32 + lhi * 8);
      sacc[0][0] = MFMA_16x16x32_BF16(kf0, qf[0][kk], sacc[0][0]);
      sacc[0][1] = MFMA_16x16x32_BF16(kf0, qf[1][kk], sacc[0][1]);
      sacc[1][0] = MFMA_16x16x32_BF16(kf1, qf[0][kk], sacc[1][0]);
      sacc[1][1] = MFMA_16x16x32_BF16(kf1, qf[1][kk], sacc[1][1]);
    }
    __builtin_amdgcn_s_setprio(0);

    s16x4 pa[2][2];
    float corr[2];
#pragma unroll
    for (int f = 0; f < 2; ++f) {
      float p[8];
      float tmax = -1e30f;
      if (last) {
        const int q = m0 + f * 16 + lrow;
#pragma unroll
        for (int g = 0; g < 2; ++g)
#pragma unroll
          for (int r = 0; r < 4; ++r) {
            const int kabs = sk0 + g * 16 + lhi * 4 + r;
            float v = sacc[g][f][r] * scale;
            if (kabs > q) v = -1e9f;
            p[g * 4 + r] = v;
            tmax = fmaxf(tmax, v);
          }
      } else {
#pragma unroll
        for (int g = 0; g < 2; ++g)
#pragma unroll
          for (int r = 0; r < 4; ++r) {
            const float v = sacc[g][f][r] * scale;
            p[g * 4 + r] = v;
            tmax = fmaxf(tmax, v);
          }
      }
      tmax = fmaxf(tmax, __shfl_xor(tmax, 16));
      tmax = fmaxf(tmax, __shfl_xor(tmax, 32));
      const float mnew = fmaxf(mst[f], tmax);
      corr[f] = __expf(mst[f] - mnew);
      float psum = 0.f;
#pragma unroll
      for (int i = 0; i < 8; ++i) { p[i] = __expf(p[i] - mnew); psum += p[i]; }
      psum += __shfl_xor(psum, 16);
      psum += __shfl_xor(psum, 32);
      lst[f] = lst[f] * corr[f] + psum;
      mst[f] = mnew;
#pragma unroll
      for (int g = 0; g < 2; ++g)
#pragma unroll
        for (int r = 0; r < 4; ++r) pa[f][g][r] = f2bf(p[g * 4 + r]);
    }

    // rescale O by corr (broadcast to accumulator row layout)
#pragma unroll
    for (int f = 0; f < 2; ++f) {
      const float c0 = __shfl(corr[f], lhi * 4 + 0);
      const float c1 = __shfl(corr[f], lhi * 4 + 1);
      const float c2 = __shfl(corr[f], lhi * 4 + 2);
      const float c3 = __shfl(corr[f], lhi * 4 + 3);
#pragma unroll
      for (int t = 0; t < 8; ++t) {
        o[f][t][0] *= c0; o[f][t][1] *= c1; o[f][t][2] *= c2; o[f][t][3] *= c3;
      }
    }

    // PV: V fragments shared across both q-fragments
    __builtin_amdgcn_s_setprio(1);
#pragma unroll
    for (int t = 0; t < 8; ++t) {
      const short* vrow = V + (size_t)(t * 16 + lrow) * 2048 + sk0 + lhi * 4;
      const s16x4 vf0 = *reinterpret_cast<const s16x4*>(vrow);
      const s16x4 vf1 = *reinterpret_cast<const s16x4*>(vrow + 16);
      o[0][t] = mfma16(pa[0][0], vf0, o[0][t]);
      o[0][t] = mfma16(pa[0][1], vf1, o[0][t]);
      o[1][t] = mfma16(pa[1][0], vf0, o[1][t]);
      o[1][t] = mfma16(pa[1][1], vf1, o[1][t]);
    }
    __builtin_amdgcn_s_setprio(0);
  }

  // epilogue: normalize by 1/l and store bf16 (b,s,h,d)
#pragma unroll
  for (int f = 0; f < 2; ++f) {
    const float linv = 1.f / lst[f];
    const float l0 = __shfl(linv, lhi * 4 + 0);
    const float l1 = __shfl(linv, lhi * 4 + 1);
    const float l2 = __shfl(linv, lhi * 4 + 2);
    const float l3 = __shfl(linv, lhi * 4 + 3);
#pragma unroll
    for (int t = 0; t < 8; ++t) {
      const size_t s_base = m0 + f * 16 + lhi * 4;
      short* dst = AO + ((size_t)b * 2048 + s_base) * 2048 + h * 128 + t * 16 + lrow;
      dst[0]        = f2bf(o[f][t][0] * l0);
      dst[2048]     = f2bf(o[f][t][1] * l1);
      dst[2 * 2048] = f2bf(o[f][t][2] * l2);
      dst[3 * 2048] = f2bf(o[f][t][3] * l3);
    }
  }
}

// ---------- launch ----------
extern "C" void kernel_launch(void* const* d_in, const int* in_sizes, int n_in,
                              void* d_out, int out_size, void* d_ws, size_t ws_size,
                              hipStream_t stream) {
  const float* hidden = (const float*)d_in[0];
  const float* rcos   = (const float*)d_in[1];
  const float* rsin   = (const float*)d_in[2];
  const float* wq     = (const float*)d_in[3];
  const float* wk     = (const float*)d_in[4];
  const float* wv     = (const float*)d_in[5];
  const float* wo     = (const float*)d_in[6];

  float* out0 = (float*)d_out;                 // (B,S,D)   8388608
  float* kout = out0 + 8388608;                // (B,H,S,hd) 8388608
  float* vout = out0 + 16777216;               // (B,H,S,hd) 8388608

  short* ws  = (short*)d_ws;
  short* Xbf = ws;                  // 8388608 bf16 (reused as attn-out AO)
  short* Wqb = ws + 8388608;        // 4194304
  short* Wkb = ws + 12582912;       // 4194304
  short* Wvb = ws + 16777216;       // 4194304
  short* Wob = ws + 20971520;       // 4194304
  short* Qp  = ws + 25165824;       // 8388608
  short* Kp  = ws + 33554432;       // 8388608
  short* Vp  = ws + 41943040;       // 8388608 (ends at 100.7 MB)
  short* Vt  = Wqb;                 // aliases Wqb+Wkb (dead after gemm_qkv)

  conv_kernel<<<8192, 256, 0, stream>>>(hidden, Xbf, 2097152);
  conv_kernel<<<4096, 256, 0, stream>>>(wq, Wqb, 1048576);
  conv_kernel<<<4096, 256, 0, stream>>>(wk, Wkb, 1048576);
  conv_kernel<<<4096, 256, 0, stream>>>(wv, Wvb, 1048576);
  conv_kernel<<<4096, 256, 0, stream>>>(wo, Wob, 1048576);

  gemm_qkv_kernel<<<dim3(16, 32, 3), 256, 0, stream>>>(Xbf, Wqb, Wkb, Wvb, Qp, Kp, Vp);

  rope_kernel<<<16384, 256, 0, stream>>>((unsigned*)Qp, (unsigned*)Kp, rcos, rsin, kout);
  vcopy_kernel<<<8192, 256, 0, stream>>>(Vp, vout);
  vtrans_kernel<<<dim3(32, 2, 32), 256, 0, stream>>>(Vp, Vt);

  attn_kernel<<<dim3(64, 16, 2), 64, 0, stream>>>(Qp, Kp, Vt, Xbf /*AO*/);

  gemm_o_kernel<<<dim3(16, 32, 1), 256, 0, stream>>>(Xbf, Wob, out0);
}

// Round 3
// 483.647 us; speedup vs baseline: 1.4951x; 1.4860x over previous
//
#include <hip/hip_runtime.h>
#include <cstdint>
#include <cmath>

// ---------- types ----------
typedef __attribute__((ext_vector_type(4))) short s16x4;
typedef __attribute__((ext_vector_type(8))) short s16x8;
typedef __attribute__((ext_vector_type(4))) float f32x4;

#define MFMA_16x16x32_BF16(a,b,c) __builtin_amdgcn_mfma_f32_16x16x32_bf16(a,b,c,0,0,0)

#if defined(__has_builtin)
#if __has_builtin(__builtin_amdgcn_mfma_f32_16x16x16bf16_1k)
#define HAVE_MFMA16 1
#endif
#endif

__device__ __forceinline__ f32x4 mfma16(s16x4 a, s16x4 b, f32x4 c) {
#ifdef HAVE_MFMA16
  return __builtin_amdgcn_mfma_f32_16x16x16bf16_1k(a, b, c, 0, 0, 0);
#else
  asm volatile("v_mfma_f32_16x16x16_bf16 %0, %1, %2, %0" : "+v"(c) : "v"(a), "v"(b));
  return c;
#endif
}

__device__ __forceinline__ short f2bf(float f) {
  union { float f; uint32_t u; } v; v.f = f;
  uint32_t r = (v.u + 0x7fffu + ((v.u >> 16) & 1u)) >> 16;
  return (short)r;
}
__device__ __forceinline__ float bf2f(short s) {
  union { float f; uint32_t u; } v; v.u = ((uint32_t)(uint16_t)s) << 16;
  return v.f;
}

#define GLOAD_LDS16(g, l) \
  __builtin_amdgcn_global_load_lds((const __attribute__((address_space(1))) void*)(g), \
                                   (__attribute__((address_space(3))) void*)(l), 16, 0, 0)

// ---------- fp32 -> bf16 conversion ----------
__global__ __launch_bounds__(256) void conv_kernel(const float* __restrict__ src,
                                                   short* __restrict__ dst, int n4) {
  int i = blockIdx.x * 256 + threadIdx.x;
  if (i >= n4) return;
  const float4 v = reinterpret_cast<const float4*>(src)[i];
  s16x4 o;
  o[0] = f2bf(v.x); o[1] = f2bf(v.y); o[2] = f2bf(v.z); o[3] = f2bf(v.w);
  reinterpret_cast<s16x4*>(dst)[i] = o;
}

// ---------- GEMM: C[M,N] = A[M,K] * Bw[N,K]^T, K=2048, ldc=2048 ----------
template <typename OutT>
__device__ __forceinline__ void gemm_body(const short* __restrict__ A,
                                          const short* __restrict__ Bw,
                                          OutT* __restrict__ C) {
  __shared__ short As[128 * 32];
  __shared__ short Bs[128 * 32];
  const int tid  = threadIdx.x;
  const int lane = tid & 63;
  const int w    = tid >> 6;
  const int lrow = lane & 15, lhi = lane >> 4;
  const int m0 = blockIdx.y * 128;
  const int n0 = blockIdx.x * 128;
  const int wm = (w >> 1) * 64, wn = (w & 1) * 64;

  f32x4 acc[4][4] = {};

  const int flat0 = w * 1024 + lane * 16;
  const int r0 = flat0 >> 6, c0 = (flat0 & 63) >> 1;
  const int flat1 = flat0 + 4096;
  const int r1 = flat1 >> 6, c1 = (flat1 & 63) >> 1;

  const short* a0 = A  + (size_t)(m0 + r0) * 2048 + c0;
  const short* a1 = A  + (size_t)(m0 + r1) * 2048 + c1;
  const short* b0 = Bw + (size_t)(n0 + r0) * 2048 + c0;
  const short* b1 = Bw + (size_t)(n0 + r1) * 2048 + c1;
  char* lA0 = (char*)As + w * 1024;
  char* lA1 = (char*)As + 4096 + w * 1024;
  char* lB0 = (char*)Bs + w * 1024;
  char* lB1 = (char*)Bs + 4096 + w * 1024;

  for (int k0 = 0; k0 < 2048; k0 += 32) {
    __syncthreads();
    GLOAD_LDS16(a0 + k0, lA0);
    GLOAD_LDS16(a1 + k0, lA1);
    GLOAD_LDS16(b0 + k0, lB0);
    GLOAD_LDS16(b1 + k0, lB1);
    __syncthreads();
    s16x8 af[4], bg[4];
#pragma unroll
    for (int i = 0; i < 4; ++i) {
      af[i] = *reinterpret_cast<const s16x8*>(As + (wm + i * 16 + lrow) * 32 + lhi * 8);
      bg[i] = *reinterpret_cast<const s16x8*>(Bs + (wn + i * 16 + lrow) * 32 + lhi * 8);
    }
#pragma unroll
    for (int i = 0; i < 4; ++i)
#pragma unroll
      for (int j = 0; j < 4; ++j)
        acc[i][j] = MFMA_16x16x32_BF16(af[i], bg[j], acc[i][j]);
  }

#pragma unroll
  for (int i = 0; i < 4; ++i) {
    const int rb = m0 + wm + i * 16 + lhi * 4;
#pragma unroll
    for (int j = 0; j < 4; ++j) {
      const int cb = n0 + wn + j * 16 + lrow;
#pragma unroll
      for (int r = 0; r < 4; ++r) {
        const float v = acc[i][j][r];
        const size_t idx = (size_t)(rb + r) * 2048 + cb;
        if constexpr (__is_same(OutT, float)) C[idx] = v;
        else                                  C[idx] = f2bf(v);
      }
    }
  }
}

__global__ __launch_bounds__(256) void gemm_qkv_kernel(const short* __restrict__ X,
                                                       const short* __restrict__ Wq,
                                                       const short* __restrict__ Wk,
                                                       const short* __restrict__ Wv,
                                                       short* __restrict__ Qp,
                                                       short* __restrict__ Kp,
                                                       short* __restrict__ Vp) {
  const short* W; short* O;
  if (blockIdx.z == 0)      { W = Wq; O = Qp; }
  else if (blockIdx.z == 1) { W = Wk; O = Kp; }
  else                      { W = Wv; O = Vp; }
  gemm_body<short>(X, W, O);
}

__global__ __launch_bounds__(256) void gemm_o_kernel(const short* __restrict__ AO,
                                                     const short* __restrict__ Wo,
                                                     float* __restrict__ out) {
  gemm_body<float>(AO, Wo, out);
}

// ---------- RoPE + fragment-packing of Q,K + fp32 k output ----------
// Packed layout per bh: [st(128)][kk(4)][lane(64)] of s16x8, where
// lane = lhi*16 + lrow encodes (row = st*16+lrow, d = kk*32 + lhi*8 .. +8).
__global__ __launch_bounds__(256) void rope_kernel(const unsigned* __restrict__ Qp,
                                                   const unsigned* __restrict__ Kp,
                                                   const float* __restrict__ rc,
                                                   const float* __restrict__ rs,
                                                   unsigned* __restrict__ Qpk,
                                                   unsigned* __restrict__ Kpk,
                                                   float* __restrict__ kout) {
  const unsigned tid = blockIdx.x * 256 + threadIdx.x;  // 2^22 total
  const int j = tid & 63;
  const int h = (tid >> 6) & 15;
  const int s = (tid >> 10) & 2047;
  const int b = tid >> 21;
  const int bh = b * 16 + h;
  const float c  = rc[s * 64 + j];
  const float sn = rs[s * 64 + j];
  const size_t half = ((size_t)(b * 2048 + s) * 2048 + h * 128) / 2 + j;

  // packed u32 index: d=2j -> st=s>>4, kk=j>>4, lhi=(j&15)>>2, word=j&3
  const size_t pk = (size_t)bh * 131072 +
      ((((size_t)(s >> 4) * 4 + (j >> 4)) * 64 + (((j & 15) >> 2) * 16 + (s & 15))) << 2) +
      (j & 3);

  const unsigned q = Qp[half];
  const float q1 = bf2f((short)(q & 0xffff)), q2 = bf2f((short)(q >> 16));
  const float qo1 = q1 * c - q2 * sn, qo2 = q1 * sn + q2 * c;
  Qpk[pk] = ((unsigned)(uint16_t)f2bf(qo1)) | (((unsigned)(uint16_t)f2bf(qo2)) << 16);

  const unsigned k = Kp[half];
  const float k1 = bf2f((short)(k & 0xffff)), k2 = bf2f((short)(k >> 16));
  const float ko1 = k1 * c - k2 * sn, ko2 = k1 * sn + k2 * c;
  Kpk[pk] = ((unsigned)(uint16_t)f2bf(ko1)) | (((unsigned)(uint16_t)f2bf(ko2)) << 16);

  const size_t kidx = (((size_t)b * 16 + h) * 2048 + s) * 128 + 2 * j;
  *reinterpret_cast<float2*>(kout + kidx) = make_float2(ko1, ko2);
}

// ---------- V: pack to PV-fragment layout + fp32 v output ----------
// Vpk per bh: [st32(64)][t(8)][g(2)][lane(64)] of s16x4:
// element = V[s = st32*32 + g*16 + lhi*4 + r][d = t*16 + lrow]
__global__ __launch_bounds__(256) void vpack_kernel(const short* __restrict__ Vp,
                                                    short* __restrict__ Vpk,
                                                    float* __restrict__ vout) {
  __shared__ short tile[64][68];
  const int bh = blockIdx.z;
  const int b = bh >> 4, h = bh & 15;
  const int s0 = blockIdx.x * 64;
  const int d0 = blockIdx.y * 64;
  const int tid = threadIdx.x;
  const int r  = tid >> 4;   // 0..15
  const int c4 = tid & 15;   // 0..15
  const short* src = Vp + ((size_t)(b * 2048 + s0) * 2048) + h * 128 + d0;
#pragma unroll
  for (int j = 0; j < 4; ++j) {
    const int row = r + j * 16;
    const s16x4 v = *reinterpret_cast<const s16x4*>(src + (size_t)row * 2048 + c4 * 4);
    *reinterpret_cast<s16x4*>(&tile[row][c4 * 4]) = v;
    float4 o;
    o.x = bf2f(v[0]); o.y = bf2f(v[1]); o.z = bf2f(v[2]); o.w = bf2f(v[3]);
    *reinterpret_cast<float4*>(vout + (((size_t)bh * 2048 + s0 + row) * 128 + d0 + c4 * 4)) = o;
  }
  __syncthreads();
  const int st32 = (s0 >> 5) + (c4 >> 3);
  const int g    = (c4 >> 2) & 1;
  const int lane = (c4 & 3) * 16 + r;
#pragma unroll
  for (int j = 0; j < 4; ++j) {
    const int drow = r + j * 16;          // d-local; t = d0/16 + j, lrow = r
    s16x4 o;
#pragma unroll
    for (int jj = 0; jj < 4; ++jj) o[jj] = tile[c4 * 4 + jj][drow];
    const size_t idx = ((((size_t)bh * 64 + st32) * 8 + (d0 >> 4) + j) * 2 + g) * 64 + lane;
    reinterpret_cast<s16x4*>(Vpk)[idx] = o;
  }
}

// ---------- online-softmax step for one 32-wide KV tile, one q-fragment ----------
__device__ __forceinline__ void softmax_step(const f32x4& sg0, const f32x4& sg1,
                                             float& mst, float& lst, f32x4* o,
                                             int qb, int sk0, int lrow, int lhi,
                                             s16x4& pa0, s16x4& pa1) {
  const float scale = 0.08838834764831845f;  // 1/sqrt(128)
  float p[8];
  const int q = qb + lrow;
  const bool domask = (sk0 + 31 > qb);
  float pmax = -1e30f;
#pragma unroll
  for (int r = 0; r < 4; ++r) {
    float v0 = sg0[r] * scale;
    float v1 = sg1[r] * scale;
    if (domask) {
      if (sk0 + lhi * 4 + r > q)      v0 = -1e9f;
      if (sk0 + 16 + lhi * 4 + r > q) v1 = -1e9f;
    }
    p[r] = v0; p[4 + r] = v1;
    pmax = fmaxf(pmax, fmaxf(v0, v1));
  }
  pmax = fmaxf(pmax, __shfl_xor(pmax, 16));
  pmax = fmaxf(pmax, __shfl_xor(pmax, 32));
  if (__any(pmax > mst + 8.f)) {               // defer-max (T13, THR=8)
    const float mnew = fmaxf(mst, pmax);
    const float corr = __expf(mst - mnew);
    mst = mnew;
    lst *= corr;
    const float c0 = __shfl(corr, lhi * 4 + 0);
    const float c1 = __shfl(corr, lhi * 4 + 1);
    const float c2 = __shfl(corr, lhi * 4 + 2);
    const float c3 = __shfl(corr, lhi * 4 + 3);
#pragma unroll
    for (int t = 0; t < 8; ++t) { o[t][0] *= c0; o[t][1] *= c1; o[t][2] *= c2; o[t][3] *= c3; }
  }
  float psum = 0.f;
#pragma unroll
  for (int i = 0; i < 8; ++i) { p[i] = __expf(p[i] - mst); psum += p[i]; }
  psum += __shfl_xor(psum, 16);
  psum += __shfl_xor(psum, 32);
  lst += psum;
#pragma unroll
  for (int r = 0; r < 4; ++r) { pa0[r] = f2bf(p[r]); pa1[r] = f2bf(p[4 + r]); }
}

// ---------- causal flash attention, diagonal-paired fragments ----------
// Wave a in [0,64) owns q rows [16a,16a+16) (frag0) and [2032-16a,2048-16a) (frag1).
// Cost (a+1)+(128-a) = 129 subtiles = constant -> perfectly balanced waves.
// All loads from fragment-packed Qpk/Kpk/Vpk: fully coalesced.
__global__ __launch_bounds__(256, 2) void attn_kernel(const short* __restrict__ Qpk,
                                                      const short* __restrict__ Kpk,
                                                      const short* __restrict__ Vpk,
                                                      short* __restrict__ AO) {
  const int lane = threadIdx.x & 63;
  const int w    = threadIdx.x >> 6;
  const int lrow = lane & 15, lhi = lane >> 4;
  const int a  = blockIdx.x * 4 + w;                 // 0..63
  const int h = blockIdx.y, b = blockIdx.z;
  const int bh = b * 16 + h;
  const int qb0 = a << 4;
  const int qb1 = 2032 - (a << 4);
  const int st0 = a, st1 = 127 - a;

  const short* Qb = Qpk + (size_t)bh * 262144;
  const short* Kb = Kpk + (size_t)bh * 262144;
  const short* Vb = Vpk + (size_t)bh * 262144;

  s16x8 qf0[4], qf1[4];
#pragma unroll
  for (int kk = 0; kk < 4; ++kk) {
    qf0[kk] = *reinterpret_cast<const s16x8*>(Qb + (((st0 * 4 + kk) * 64 + lane) << 3));
    qf1[kk] = *reinterpret_cast<const s16x8*>(Qb + (((st1 * 4 + kk) * 64 + lane) << 3));
  }

  f32x4 o0[8] = {}, o1[8] = {};
  float m0s = -INFINITY, m1s = -INFINITY, l0s = 0.f, l1s = 0.f;
  const int nkb = (qb1 + 47) >> 5;   // ceil((qb1+16)/32)

  for (int kt = 0; kt < nkb; ++kt) {
    const int sk0 = kt << 5;
    const bool act0 = (sk0 <= qb0);

    // --- issue all loads for this tile (coalesced, independent of compute) ---
    s16x8 kf[2][4];
    const short* kbase = Kb + (((size_t)(sk0 >> 4) * 4 * 64 + lane) << 3);
#pragma unroll
    for (int g = 0; g < 2; ++g)
#pragma unroll
      for (int kk = 0; kk < 4; ++kk)
        kf[g][kk] = *reinterpret_cast<const s16x8*>(kbase + (((g * 4 + kk) * 64) << 3));
    s16x4 vf[8][2];
    const short* vbase = Vb + (((size_t)(sk0 >> 5) * 16 * 64 + lane) << 2);
#pragma unroll
    for (int t = 0; t < 8; ++t)
#pragma unroll
      for (int g = 0; g < 2; ++g)
        vf[t][g] = *reinterpret_cast<const s16x4*>(vbase + (((t * 2 + g) * 64) << 2));

    // --- QK^T (swapped: mfma(K,Q) -> S^T) ---
    f32x4 s00 = {}, s10 = {}, s01 = {}, s11 = {};
    __builtin_amdgcn_s_setprio(1);
    if (act0) {
#pragma unroll
      for (int kk = 0; kk < 4; ++kk) {
        s01 = MFMA_16x16x32_BF16(kf[0][kk], qf1[kk], s01);
        s11 = MFMA_16x16x32_BF16(kf[1][kk], qf1[kk], s11);
        s00 = MFMA_16x16x32_BF16(kf[0][kk], qf0[kk], s00);
        s10 = MFMA_16x16x32_BF16(kf[1][kk], qf0[kk], s10);
      }
    } else {
#pragma unroll
      for (int kk = 0; kk < 4; ++kk) {
        s01 = MFMA_16x16x32_BF16(kf[0][kk], qf1[kk], s01);
        s11 = MFMA_16x16x32_BF16(kf[1][kk], qf1[kk], s11);
      }
    }
    __builtin_amdgcn_s_setprio(0);

    // --- softmax ---
    s16x4 pa00, pa01, pa10, pa11;
    softmax_step(s01, s11, m1s, l1s, o1, qb1, sk0, lrow, lhi, pa10, pa11);
    if (act0)
      softmax_step(s00, s10, m0s, l0s, o0, qb0, sk0, lrow, lhi, pa00, pa01);

    // --- PV (V fragments shared across both q-fragments) ---
    __builtin_amdgcn_s_setprio(1);
    if (act0) {
#pragma unroll
      for (int t = 0; t < 8; ++t) {
        o1[t] = mfma16(pa10, vf[t][0], o1[t]);
        o1[t] = mfma16(pa11, vf[t][1], o1[t]);
        o0[t] = mfma16(pa00, vf[t][0], o0[t]);
        o0[t] = mfma16(pa01, vf[t][1], o0[t]);
      }
    } else {
#pragma unroll
      for (int t = 0; t < 8; ++t) {
        o1[t] = mfma16(pa10, vf[t][0], o1[t]);
        o1[t] = mfma16(pa11, vf[t][1], o1[t]);
      }
    }
    __builtin_amdgcn_s_setprio(0);
  }

  // --- epilogue: normalize, store bf16 (b,s,h,d) ---
#pragma unroll
  for (int f = 0; f < 2; ++f) {
    const float linv = 1.f / (f ? l1s : l0s);
    const int qb = f ? qb1 : qb0;
    f32x4* o = f ? o1 : o0;
    const float e0 = __shfl(linv, lhi * 4 + 0);
    const float e1 = __shfl(linv, lhi * 4 + 1);
    const float e2 = __shfl(linv, lhi * 4 + 2);
    const float e3 = __shfl(linv, lhi * 4 + 3);
#pragma unroll
    for (int t = 0; t < 8; ++t) {
      short* dst = AO + ((size_t)b * 2048 + qb + lhi * 4) * 2048 + h * 128 + t * 16 + lrow;
      dst[0]        = f2bf(o[t][0] * e0);
      dst[2048]     = f2bf(o[t][1] * e1);
      dst[2 * 2048] = f2bf(o[t][2] * e2);
      dst[3 * 2048] = f2bf(o[t][3] * e3);
    }
  }
}

// ---------- launch ----------
extern "C" void kernel_launch(void* const* d_in, const int* in_sizes, int n_in,
                              void* d_out, int out_size, void* d_ws, size_t ws_size,
                              hipStream_t stream) {
  const float* hidden = (const float*)d_in[0];
  const float* rcos   = (const float*)d_in[1];
  const float* rsin   = (const float*)d_in[2];
  const float* wq     = (const float*)d_in[3];
  const float* wk     = (const float*)d_in[4];
  const float* wv     = (const float*)d_in[5];
  const float* wo     = (const float*)d_in[6];

  float* out0 = (float*)d_out;                 // (B,S,D)    8388608
  float* kout = out0 + 8388608;                // (B,H,S,hd) 8388608
  float* vout = out0 + 16777216;               // (B,H,S,hd) 8388608

  short* ws  = (short*)d_ws;
  short* Xbf = ws;                  // 8388608
  short* Wqb = ws + 8388608;        // 4194304
  short* Wkb = ws + 12582912;       // 4194304
  short* Wvb = ws + 16777216;       // 4194304
  short* Wob = ws + 20971520;       // 4194304
  short* Qp  = ws + 25165824;       // 8388608
  short* Kp  = ws + 33554432;       // 8388608
  short* Vp  = ws + 41943040;       // 8388608 (ends at 100.7 MB)
  // aliases (dead-buffer reuse):
  short* Qpk = Wqb;                 // 8388608, spans Wqb+Wkb (dead after gemm_qkv)
  short* Kpk = Xbf;                 // 8388608 (X dead after gemm_qkv)
  short* Vpk = Qp;                  // 8388608 (Qp dead after rope)
  short* AO  = Kp;                  // 8388608 (Kp dead after rope)

  conv_kernel<<<8192, 256, 0, stream>>>(hidden, Xbf, 2097152);
  conv_kernel<<<4096, 256, 0, stream>>>(wq, Wqb, 1048576);
  conv_kernel<<<4096, 256, 0, stream>>>(wk, Wkb, 1048576);
  conv_kernel<<<4096, 256, 0, stream>>>(wv, Wvb, 1048576);
  conv_kernel<<<4096, 256, 0, stream>>>(wo, Wob, 1048576);

  gemm_qkv_kernel<<<dim3(16, 32, 3), 256, 0, stream>>>(Xbf, Wqb, Wkb, Wvb, Qp, Kp, Vp);

  rope_kernel<<<16384, 256, 0, stream>>>((const unsigned*)Qp, (const unsigned*)Kp,
                                         rcos, rsin, (unsigned*)Qpk, (unsigned*)Kpk, kout);
  vpack_kernel<<<dim3(32, 2, 32), 256, 0, stream>>>(Vp, Vpk, vout);

  attn_kernel<<<dim3(16, 16, 2), 256, 0, stream>>>(Qpk, Kpk, Vpk, AO);

  gemm_o_kernel<<<dim3(16, 32, 1), 256, 0, stream>>>(AO, Wob, out0);
}